// Round 3
// baseline (4438.123 us; speedup 1.0000x reference)
//
#include <hip/hip_runtime.h>
#include <hip/hip_bf16.h>

#define N_NODES 100000
#define N_EDGES 1600000
#define IN_DIM  128
#define HID_DIM 128
#define OUT_DIM 64

__device__ __forceinline__ float eluf(float x) { return x > 0.0f ? x : expm1f(x); }

// ---- edge_index dtype probe: int64 data has all-zero odd int32 words ----
__global__ void k_detect(const int* __restrict__ ei, int* __restrict__ flag) {
    __shared__ int acc;
    if (threadIdx.x == 0) acc = 0;
    __syncthreads();
    int v = 0;
    for (int e = threadIdx.x; e < 1024; e += 256) v |= ei[2 * e + 1];
    atomicOr(&acc, v);
    __syncthreads();
    if (threadIdx.x == 0) flag[0] = (acc == 0) ? 1 : 0;
}

__device__ __forceinline__ int esrc(const int* ei, int e, int is64) {
    return is64 ? ei[2 * e] : ei[e];
}
__device__ __forceinline__ int edst(const int* ei, int e, int is64) {
    return is64 ? ei[2 * (N_EDGES + e)] : ei[N_EDGES + e];
}

// ---------------- degree / dinv ----------------
__global__ void k_deg_init(float* __restrict__ deg) {
    int i = blockIdx.x * blockDim.x + threadIdx.x;
    if (i < N_NODES) deg[i] = 1.0f;  // self-loop contributes 1
}
__global__ void k_deg_count(const int* __restrict__ ei, const int* __restrict__ flag,
                            float* __restrict__ deg) {
    int e = blockIdx.x * blockDim.x + threadIdx.x;
    if (e < N_EDGES) atomicAdd(&deg[edst(ei, e, flag[0])], 1.0f);
}
__global__ void k_dinv(float* __restrict__ deg) {
    int i = blockIdx.x * blockDim.x + threadIdx.x;
    if (i < N_NODES) deg[i] = rsqrtf(deg[i]);  // deg >= 1
}

// ---- self-loop init: agg[i][:] = x[i][:] * dinv[i]^2 (full overwrite of poison) ----
__global__ void k_selfinit_x(const float4* __restrict__ x4, const float* __restrict__ dinv,
                             float4* __restrict__ agg) {
    int i = blockIdx.x * blockDim.x + threadIdx.x;  // one float4 (4 cols)
    const int total = N_NODES * (IN_DIM / 4);
    if (i >= total) return;
    int node = i >> 5;  // / (IN_DIM/4)
    float s = dinv[node]; s = s * s;
    float4 v = x4[i];
    v.x *= s; v.y *= s; v.z *= s; v.w *= s;
    agg[i] = v;
}

// ---- edge scatter: agg[dst] += x[src] * dinv[src]*dinv[dst]; 32 lanes/edge ----
__global__ void k_scatter_x(const float4* __restrict__ x4, const float* __restrict__ dinv,
                            const int* __restrict__ ei, const int* __restrict__ flag,
                            float* __restrict__ agg) {
    int tid = blockIdx.x * blockDim.x + threadIdx.x;
    int e = tid >> 5;
    int p = tid & 31;
    if (e >= N_EDGES) return;
    int is64 = flag[0];
    int s = esrc(ei, e, is64), d = edst(ei, e, is64);
    float norm = dinv[s] * dinv[d];
    float4 v = x4[(long long)s * (IN_DIM / 4) + p];
    float* a = agg + (long long)d * IN_DIM + p * 4;
    atomicAdd(a + 0, v.x * norm);
    atomicAdd(a + 1, v.y * norm);
    atomicAdd(a + 2, v.z * norm);
    atomicAdd(a + 3, v.w * norm);
}

// ---- GEMM1 in place: big[r,:] = elu(big[r,:] @ W1 + b1) ----
__launch_bounds__(256)
__global__ void k_gemm1(float* __restrict__ big, const float4* __restrict__ Wp4,
                        const float* __restrict__ b) {
    __shared__ float4 ws4[IN_DIM][HID_DIM / 4];  // 64 KB
    __shared__ float xs[8][IN_DIM];              // 4 KB
    __shared__ float bs[HID_DIM];
    int t = threadIdx.x;
    for (int i = t; i < IN_DIM * HID_DIM / 4; i += 256) ws4[i >> 5][i & 31] = Wp4[i];
    if (t < HID_DIM) bs[t] = b[t];
    int tx = t & 31, ty = t >> 5;
    for (int g = blockIdx.x; g < N_NODES / 8; g += gridDim.x) {
        long long base = (long long)g * 8 * IN_DIM;
        __syncthreads();  // xs reuse guard; first iter covers ws4/bs stores
        ((float4*)xs)[t] = *((const float4*)(big + base) + t);  // 256 float4 = 8x128
        __syncthreads();
        float a0 = 0.f, a1 = 0.f, a2 = 0.f, a3 = 0.f;
#pragma unroll 4
        for (int k = 0; k < IN_DIM; k++) {
            float xv = xs[ty][k];
            float4 w = ws4[k][tx];
            a0 += xv * w.x; a1 += xv * w.y; a2 += xv * w.z; a3 += xv * w.w;
        }
        int c = 4 * tx;
        float4 r = { eluf(a0 + bs[c]), eluf(a1 + bs[c + 1]),
                     eluf(a2 + bs[c + 2]), eluf(a3 + bs[c + 3]) };
        *(float4*)(big + base + (long long)ty * IN_DIM + c) = r;
    }
}

// ---- GEMM2: h2 (fp32, staged in d_out) = h1 @ W2 (bias/elu after aggregation) ----
__launch_bounds__(256)
__global__ void k_gemm2(const float* __restrict__ big, const float2* __restrict__ Wp2,
                        float2* __restrict__ h2out) {
    __shared__ float2 ws2[HID_DIM][OUT_DIM / 2];  // 32 KB
    __shared__ float xs[8][HID_DIM];              // 4 KB
    int t = threadIdx.x;
    for (int i = t; i < HID_DIM * OUT_DIM / 2; i += 256) ws2[i >> 5][i & 31] = Wp2[i];
    int tx = t & 31, ty = t >> 5;
    for (int g = blockIdx.x; g < N_NODES / 8; g += gridDim.x) {
        long long base = (long long)g * 8 * HID_DIM;
        __syncthreads();
        ((float4*)xs)[t] = *((const float4*)(big + base) + t);
        __syncthreads();
        float a0 = 0.f, a1 = 0.f;
#pragma unroll 4
        for (int k = 0; k < HID_DIM; k++) {
            float xv = xs[ty][k];
            float2 w = ws2[k][tx];
            a0 += xv * w.x; a1 += xv * w.y;
        }
        float2 r = { a0, a1 };
        h2out[(long long)(g * 8 + ty) * (OUT_DIM / 2) + tx] = r;
    }
}

// ---- self-loop init over h2: agg2 = h2 * dinv^2 ----
__global__ void k_selfinit_h2(const float4* __restrict__ h2, const float* __restrict__ dinv,
                              float4* __restrict__ agg) {
    int i = blockIdx.x * blockDim.x + threadIdx.x;
    const int total = N_NODES * (OUT_DIM / 4);
    if (i >= total) return;
    int node = i >> 4;
    float s = dinv[node]; s = s * s;
    float4 v = h2[i];
    v.x *= s; v.y *= s; v.z *= s; v.w *= s;
    agg[i] = v;
}

// ---- edge scatter over h2: 16 lanes/edge ----
__global__ void k_scatter_h2(const float4* __restrict__ h2, const float* __restrict__ dinv,
                             const int* __restrict__ ei, const int* __restrict__ flag,
                             float* __restrict__ agg) {
    int tid = blockIdx.x * blockDim.x + threadIdx.x;
    int e = tid >> 4;
    int p = tid & 15;
    if (e >= N_EDGES) return;
    int is64 = flag[0];
    int s = esrc(ei, e, is64), d = edst(ei, e, is64);
    float norm = dinv[s] * dinv[d];
    float4 v = h2[(long long)s * (OUT_DIM / 4) + p];
    float* a = agg + (long long)d * OUT_DIM + p * 4;
    atomicAdd(a + 0, v.x * norm);
    atomicAdd(a + 1, v.y * norm);
    atomicAdd(a + 2, v.z * norm);
    atomicAdd(a + 3, v.w * norm);
}

// ---- final: out (fp32, overwrite d_out) = elu(agg2 + b2) ----
__global__ void k_final(const float4* __restrict__ agg, const float* __restrict__ b,
                        float4* __restrict__ out) {
    int i = blockIdx.x * blockDim.x + threadIdx.x;
    const int total = N_NODES * (OUT_DIM / 4);
    if (i >= total) return;
    int cb = (i & 15) * 4;
    float4 v = agg[i];
    float4 r = { eluf(v.x + b[cb + 0]), eluf(v.y + b[cb + 1]),
                 eluf(v.z + b[cb + 2]), eluf(v.w + b[cb + 3]) };
    out[i] = r;
}

extern "C" void kernel_launch(void* const* d_in, const int* in_sizes, int n_in,
                              void* d_out, int out_size, void* d_ws, size_t ws_size,
                              hipStream_t stream) {
    const float* x  = (const float*)d_in[0];
    const int*   ei = (const int*)d_in[1];
    const float* W1 = (const float*)d_in[2];
    const float* b1 = (const float*)d_in[3];
    const float* W2 = (const float*)d_in[4];
    const float* b2 = (const float*)d_in[5];

    // workspace: flag+dinv (131136 floats) + one N*128 fp32 buffer = 51.7 MB
    const size_t needed = ((size_t)131136 + (size_t)N_NODES * IN_DIM) * sizeof(float);
    if (ws_size < needed) return;  // canary: leaves out=0 -> finite absmax, not NaN

    int*   flag = (int*)d_ws;
    float* dinv = (float*)d_ws + 64;
    float* big  = (float*)d_ws + 131136;  // aggX -> h1 (in-place); [0:N*64) reused as agg2
    float* h2   = (float*)d_out;          // h2 staged fp32 in d_out, overwritten by k_final

    k_detect<<<1, 256, 0, stream>>>(ei, flag);
    k_deg_init<<<(N_NODES + 255) / 256, 256, 0, stream>>>(dinv);
    k_deg_count<<<(N_EDGES + 255) / 256, 256, 0, stream>>>(ei, flag, dinv);
    k_dinv<<<(N_NODES + 255) / 256, 256, 0, stream>>>(dinv);

    // layer 1: aggregate x first (linearity), then in-place GEMM + bias + ELU
    k_selfinit_x<<<(N_NODES * (IN_DIM / 4) + 255) / 256, 256, 0, stream>>>((const float4*)x, dinv, (float4*)big);
    k_scatter_x<<<(N_EDGES * 32 + 255) / 256, 256, 0, stream>>>((const float4*)x, dinv, ei, flag, big);
    k_gemm1<<<1024, 256, 0, stream>>>(big, (const float4*)W1, b1);

    // layer 2: GEMM into d_out (fp32), aggregate into big[0:N*64), finalize
    k_gemm2<<<1024, 256, 0, stream>>>(big, (const float2*)W2, (float2*)h2);
    k_selfinit_h2<<<(N_NODES * (OUT_DIM / 4) + 255) / 256, 256, 0, stream>>>((const float4*)h2, dinv, (float4*)big);
    k_scatter_h2<<<(N_EDGES * 16 + 255) / 256, 256, 0, stream>>>((const float4*)h2, dinv, ei, flag, big);
    k_final<<<(N_NODES * (OUT_DIM / 4) + 255) / 256, 256, 0, stream>>>((const float4*)big, b2, (float4*)d_out);
}

// Round 4
// 686.265 us; speedup vs baseline: 6.4671x; 6.4671x over previous
//
#include <hip/hip_runtime.h>
#include <hip/hip_bf16.h>

#define N_NODES 100000
#define N_EDGES 1600000
#define IN_DIM  128
#define HID_DIM 128
#define OUT_DIM 64
#define SCAN_CHUNK 1024
#define NBLK_SCAN ((N_NODES + SCAN_CHUNK - 1) / SCAN_CHUNK)  // 98

__device__ __forceinline__ float eluf(float x) { return x > 0.0f ? x : expm1f(x); }

// ---- edge_index dtype probe: int64 data has all-zero odd int32 words ----
__global__ void k_detect(const int* __restrict__ ei, int* __restrict__ flag) {
    __shared__ int acc;
    if (threadIdx.x == 0) acc = 0;
    __syncthreads();
    int v = 0;
    for (int e = threadIdx.x; e < 1024; e += 256) v |= ei[2 * e + 1];
    atomicOr(&acc, v);
    __syncthreads();
    if (threadIdx.x == 0) flag[0] = (acc == 0) ? 1 : 0;
}
__device__ __forceinline__ int esrc(const int* ei, int e, int is64) {
    return is64 ? ei[2 * e] : ei[e];
}
__device__ __forceinline__ int edst(const int* ei, int e, int is64) {
    return is64 ? ei[2 * (N_EDGES + e)] : ei[N_EDGES + e];
}

// =================== CSR build ===================
__global__ void k_zero_int(int* __restrict__ p, int n) {
    int i = blockIdx.x * blockDim.x + threadIdx.x;
    if (i < n) p[i] = 0;
}
__global__ void k_deg_count_i(const int* __restrict__ ei, const int* __restrict__ flag,
                              int* __restrict__ deg) {
    int e = blockIdx.x * blockDim.x + threadIdx.x;
    if (e < N_EDGES) atomicAdd(&deg[edst(ei, e, flag[0])], 1);
}
__global__ void k_dinv_i(const int* __restrict__ deg, float* __restrict__ dinv) {
    int i = blockIdx.x * blockDim.x + threadIdx.x;
    if (i < N_NODES) dinv[i] = rsqrtf((float)(deg[i] + 1));  // +1 self-loop
}
__global__ void k_scan1(const int* __restrict__ deg, int* __restrict__ rowStart,
                        int* __restrict__ bsum) {
    __shared__ int sd[256];
    int t = threadIdx.x, blk = blockIdx.x;
    int i0 = blk * SCAN_CHUNK + t * 4;
    int d0 = (i0 + 0 < N_NODES) ? deg[i0 + 0] : 0;
    int d1 = (i0 + 1 < N_NODES) ? deg[i0 + 1] : 0;
    int d2 = (i0 + 2 < N_NODES) ? deg[i0 + 2] : 0;
    int d3 = (i0 + 3 < N_NODES) ? deg[i0 + 3] : 0;
    int s4 = d0 + d1 + d2 + d3;
    sd[t] = s4;
    __syncthreads();
    int acc = s4;
    for (int off = 1; off < 256; off <<= 1) {
        int v = (t >= off) ? sd[t - off] : 0;
        __syncthreads();
        acc += v; sd[t] = acc;
        __syncthreads();
    }
    int excl = acc - s4;
    if (i0 + 0 < N_NODES) rowStart[i0 + 0] = excl;
    if (i0 + 1 < N_NODES) rowStart[i0 + 1] = excl + d0;
    if (i0 + 2 < N_NODES) rowStart[i0 + 2] = excl + d0 + d1;
    if (i0 + 3 < N_NODES) rowStart[i0 + 3] = excl + d0 + d1 + d2;
    if (t == 255) bsum[blk] = acc;
}
__global__ void k_scan2(int* __restrict__ bsum, int* __restrict__ rowStartN) {
    int run = 0;
    for (int b = 0; b < NBLK_SCAN; b++) { int v = bsum[b]; bsum[b] = run; run += v; }
    rowStartN[0] = run;
}
__global__ void k_scan3(int* __restrict__ rowStart, const int* __restrict__ bsum) {
    int i = blockIdx.x * blockDim.x + threadIdx.x;
    if (i < N_NODES) rowStart[i] += bsum[i >> 10];
}
__global__ void k_fill(const int* __restrict__ ei, const int* __restrict__ flag,
                       const int* __restrict__ rowStart, int* __restrict__ cursor,
                       int* __restrict__ csr) {
    int e = blockIdx.x * blockDim.x + threadIdx.x;
    if (e >= N_EDGES) return;
    int is64 = flag[0];
    int s = esrc(ei, e, is64), d = edst(ei, e, is64);
    int pos = atomicAdd(&cursor[d], 1);
    csr[rowStart[d] + pos] = s;
}

// =================== pull-mode aggregation ===================
// one wave per node; lane l holds float2 (cols 2l,2l+1) of the 128-wide row
__launch_bounds__(256)
__global__ void k_gather1(const float2* __restrict__ x2, const float* __restrict__ dinv,
                          const int* __restrict__ rowStart, const int* __restrict__ csr,
                          float2* __restrict__ agg) {
    int w = (blockIdx.x * blockDim.x + threadIdx.x) >> 6;
    int lane = threadIdx.x & 63;
    if (w >= N_NODES) return;
    int beg = rowStart[w], end = rowStart[w + 1];
    float dd = dinv[w];
    float2 v = x2[(long long)w * 64 + lane];
    float2 acc = { v.x * dd, v.y * dd };  // self-loop: x dinv^2 (outer dd applied below)
    int j = beg;
    for (; j + 2 <= end; j += 2) {
        int s0 = csr[j], s1 = csr[j + 1];
        float w0 = dinv[s0], w1 = dinv[s1];
        float2 v0 = x2[(long long)s0 * 64 + lane];
        float2 v1 = x2[(long long)s1 * 64 + lane];
        acc.x += v0.x * w0 + v1.x * w1;
        acc.y += v0.y * w0 + v1.y * w1;
    }
    if (j < end) {
        int s0 = csr[j];
        float w0 = dinv[s0];
        float2 v0 = x2[(long long)s0 * 64 + lane];
        acc.x += v0.x * w0; acc.y += v0.y * w0;
    }
    acc.x *= dd; acc.y *= dd;
    agg[(long long)w * 64 + lane] = acc;
}

// one wave per node over h2 (64 cols, stride `stride` floats); fused bias+ELU -> out
__launch_bounds__(256)
__global__ void k_gather2(const float* __restrict__ h2, const float* __restrict__ dinv,
                          const int* __restrict__ rowStart, const int* __restrict__ csr,
                          const float* __restrict__ b2, float* __restrict__ out, int stride) {
    int w = (blockIdx.x * blockDim.x + threadIdx.x) >> 6;
    int lane = threadIdx.x & 63;
    if (w >= N_NODES) return;
    int beg = rowStart[w], end = rowStart[w + 1];
    float dd = dinv[w];
    float acc = h2[(long long)w * stride + lane] * dd;
    int j = beg;
    for (; j + 2 <= end; j += 2) {
        int s0 = csr[j], s1 = csr[j + 1];
        float w0 = dinv[s0], w1 = dinv[s1];
        acc += h2[(long long)s0 * stride + lane] * w0
             + h2[(long long)s1 * stride + lane] * w1;
    }
    if (j < end) {
        int s0 = csr[j];
        acc += h2[(long long)s0 * stride + lane] * dinv[s0];
    }
    acc *= dd;
    out[(long long)w * OUT_DIM + lane] = eluf(acc + b2[lane]);
}

// =================== GEMMs ===================
// in place: big[r,:] = elu(big[r,:] @ W1 + b1)
__launch_bounds__(256)
__global__ void k_gemm1(float* __restrict__ big, const float4* __restrict__ Wp4,
                        const float* __restrict__ b) {
    __shared__ float4 ws4[IN_DIM][HID_DIM / 4];  // 64 KB
    __shared__ float xs[8][IN_DIM];              // 4 KB
    __shared__ float bs[HID_DIM];
    int t = threadIdx.x;
    for (int i = t; i < IN_DIM * HID_DIM / 4; i += 256) ws4[i >> 5][i & 31] = Wp4[i];
    if (t < HID_DIM) bs[t] = b[t];
    int tx = t & 31, ty = t >> 5;
    for (int g = blockIdx.x; g < N_NODES / 8; g += gridDim.x) {
        long long base = (long long)g * 8 * IN_DIM;
        __syncthreads();
        ((float4*)xs)[t] = *((const float4*)(big + base) + t);
        __syncthreads();
        float a0 = 0.f, a1 = 0.f, a2 = 0.f, a3 = 0.f;
#pragma unroll 4
        for (int k = 0; k < IN_DIM; k++) {
            float xv = xs[ty][k];
            float4 w = ws4[k][tx];
            a0 += xv * w.x; a1 += xv * w.y; a2 += xv * w.z; a3 += xv * w.w;
        }
        int c = 4 * tx;
        float4 r = { eluf(a0 + bs[c]), eluf(a1 + bs[c + 1]),
                     eluf(a2 + bs[c + 2]), eluf(a3 + bs[c + 3]) };
        *(float4*)(big + base + (long long)ty * IN_DIM + c) = r;
    }
}

// h2[r, 0:64) = h1[r,:] @ W2   (out stride parametrized; safe in-place into big)
__launch_bounds__(256)
__global__ void k_gemm2(const float* __restrict__ big, const float2* __restrict__ Wp2,
                        float* __restrict__ outp, int ostride) {
    __shared__ float2 ws2[HID_DIM][OUT_DIM / 2];  // 32 KB
    __shared__ float xs[8][HID_DIM];              // 4 KB
    int t = threadIdx.x;
    for (int i = t; i < HID_DIM * OUT_DIM / 2; i += 256) ws2[i >> 5][i & 31] = Wp2[i];
    int tx = t & 31, ty = t >> 5;
    for (int g = blockIdx.x; g < N_NODES / 8; g += gridDim.x) {
        long long base = (long long)g * 8 * HID_DIM;
        __syncthreads();
        ((float4*)xs)[t] = *((const float4*)(big + base) + t);
        __syncthreads();
        float a0 = 0.f, a1 = 0.f;
#pragma unroll 4
        for (int k = 0; k < HID_DIM; k++) {
            float xv = xs[ty][k];
            float2 w = ws2[k][tx];
            a0 += xv * w.x; a1 += xv * w.y;
        }
        float2 r = { a0, a1 };
        *(float2*)(outp + (long long)(g * 8 + ty) * ostride + 2 * tx) = r;
    }
}

// =================== fallback (round-3 atomic push path) ===================
__global__ void k_deg_init_f(float* __restrict__ deg) {
    int i = blockIdx.x * blockDim.x + threadIdx.x;
    if (i < N_NODES) deg[i] = 1.0f;
}
__global__ void k_deg_count_f(const int* __restrict__ ei, const int* __restrict__ flag,
                              float* __restrict__ deg) {
    int e = blockIdx.x * blockDim.x + threadIdx.x;
    if (e < N_EDGES) atomicAdd(&deg[edst(ei, e, flag[0])], 1.0f);
}
__global__ void k_dinv_f(float* __restrict__ deg) {
    int i = blockIdx.x * blockDim.x + threadIdx.x;
    if (i < N_NODES) deg[i] = rsqrtf(deg[i]);
}
__global__ void k_selfinit_x(const float4* __restrict__ x4, const float* __restrict__ dinv,
                             float4* __restrict__ agg) {
    int i = blockIdx.x * blockDim.x + threadIdx.x;
    const int total = N_NODES * (IN_DIM / 4);
    if (i >= total) return;
    int node = i >> 5;
    float s = dinv[node]; s = s * s;
    float4 v = x4[i];
    v.x *= s; v.y *= s; v.z *= s; v.w *= s;
    agg[i] = v;
}
__global__ void k_scatter_x(const float4* __restrict__ x4, const float* __restrict__ dinv,
                            const int* __restrict__ ei, const int* __restrict__ flag,
                            float* __restrict__ agg) {
    int tid = blockIdx.x * blockDim.x + threadIdx.x;
    int e = tid >> 5, p = tid & 31;
    if (e >= N_EDGES) return;
    int is64 = flag[0];
    int s = esrc(ei, e, is64), d = edst(ei, e, is64);
    float norm = dinv[s] * dinv[d];
    float4 v = x4[(long long)s * (IN_DIM / 4) + p];
    float* a = agg + (long long)d * IN_DIM + p * 4;
    atomicAdd(a + 0, v.x * norm); atomicAdd(a + 1, v.y * norm);
    atomicAdd(a + 2, v.z * norm); atomicAdd(a + 3, v.w * norm);
}
__global__ void k_selfinit_h2(const float4* __restrict__ h2, const float* __restrict__ dinv,
                              float4* __restrict__ agg) {
    int i = blockIdx.x * blockDim.x + threadIdx.x;
    const int total = N_NODES * (OUT_DIM / 4);
    if (i >= total) return;
    int node = i >> 4;
    float s = dinv[node]; s = s * s;
    float4 v = h2[i];
    v.x *= s; v.y *= s; v.z *= s; v.w *= s;
    agg[i] = v;
}
__global__ void k_scatter_h2(const float4* __restrict__ h2, const float* __restrict__ dinv,
                             const int* __restrict__ ei, const int* __restrict__ flag,
                             float* __restrict__ agg) {
    int tid = blockIdx.x * blockDim.x + threadIdx.x;
    int e = tid >> 4, p = tid & 15;
    if (e >= N_EDGES) return;
    int is64 = flag[0];
    int s = esrc(ei, e, is64), d = edst(ei, e, is64);
    float norm = dinv[s] * dinv[d];
    float4 v = h2[(long long)s * (OUT_DIM / 4) + p];
    float* a = agg + (long long)d * OUT_DIM + p * 4;
    atomicAdd(a + 0, v.x * norm); atomicAdd(a + 1, v.y * norm);
    atomicAdd(a + 2, v.z * norm); atomicAdd(a + 3, v.w * norm);
}
__global__ void k_final(const float4* __restrict__ agg, const float* __restrict__ b,
                        float4* __restrict__ out) {
    int i = blockIdx.x * blockDim.x + threadIdx.x;
    const int total = N_NODES * (OUT_DIM / 4);
    if (i >= total) return;
    int cb = (i & 15) * 4;
    float4 v = agg[i];
    float4 r = { eluf(v.x + b[cb + 0]), eluf(v.y + b[cb + 1]),
                 eluf(v.z + b[cb + 2]), eluf(v.w + b[cb + 3]) };
    out[i] = r;
}

extern "C" void kernel_launch(void* const* d_in, const int* in_sizes, int n_in,
                              void* d_out, int out_size, void* d_ws, size_t ws_size,
                              hipStream_t stream) {
    const float* x  = (const float*)d_in[0];
    const int*   ei = (const int*)d_in[1];
    const float* W1 = (const float*)d_in[2];
    const float* b1 = (const float*)d_in[3];
    const float* W2 = (const float*)d_in[4];
    const float* b2 = (const float*)d_in[5];

    // ---- layout (4-byte units) ----
    // flag:16 | deg/cursor:100000 | rowStart:100001 | pad | bsum:128 | pad |
    // csr:1600000 | dinv:100000 | pad | big: N*128
    const size_t OFF_FLAG = 0, OFF_DEG = 16, OFF_ROW = 100016, OFF_BSUM = 200032,
                 OFF_CSR = 200192, OFF_DINV = 1800192, OFF_BIG = 1900288;
    const size_t needed_pull = (OFF_BIG + (size_t)N_NODES * IN_DIM) * 4;
    const size_t needed_fb   = ((size_t)131136 + (size_t)N_NODES * IN_DIM) * 4;

    if (ws_size >= needed_pull) {
        int*   flag = (int*)d_ws + OFF_FLAG;
        int*   deg  = (int*)d_ws + OFF_DEG;   // reused as cursor after scan
        int*   row  = (int*)d_ws + OFF_ROW;
        int*   bsum = (int*)d_ws + OFF_BSUM;
        int*   csr  = (int*)d_ws + OFF_CSR;
        float* dinv = (float*)d_ws + OFF_DINV;
        float* big  = (float*)d_ws + OFF_BIG;

        k_detect<<<1, 256, 0, stream>>>(ei, flag);
        k_zero_int<<<(N_NODES + 255) / 256, 256, 0, stream>>>(deg, N_NODES);
        k_deg_count_i<<<(N_EDGES + 255) / 256, 256, 0, stream>>>(ei, flag, deg);
        k_dinv_i<<<(N_NODES + 255) / 256, 256, 0, stream>>>(deg, dinv);
        k_scan1<<<NBLK_SCAN, 256, 0, stream>>>(deg, row, bsum);
        k_scan2<<<1, 1, 0, stream>>>(bsum, row + N_NODES);
        k_scan3<<<(N_NODES + 255) / 256, 256, 0, stream>>>(row, bsum);
        k_zero_int<<<(N_NODES + 255) / 256, 256, 0, stream>>>(deg, N_NODES);
        k_fill<<<(N_EDGES + 255) / 256, 256, 0, stream>>>(ei, flag, row, deg, csr);

        // layer 1: pull-aggregate x -> big, then in-place GEMM+bias+ELU
        k_gather1<<<(N_NODES * 64 + 255) / 256, 256, 0, stream>>>(
            (const float2*)x, dinv, row, csr, (float2*)big);
        k_gemm1<<<1024, 256, 0, stream>>>(big, (const float4*)W1, b1);
        // layer 2: GEMM in-place (h2 in first 64 cols, stride 128), pull-aggregate+bias+ELU -> out
        k_gemm2<<<1024, 256, 0, stream>>>(big, (const float2*)W2, big, IN_DIM);
        k_gather2<<<(N_NODES * 64 + 255) / 256, 256, 0, stream>>>(
            big, dinv, row, csr, b2, (float*)d_out, IN_DIM);
    } else if (ws_size >= needed_fb) {
        int*   flag = (int*)d_ws;
        float* dinv = (float*)d_ws + 64;
        float* big  = (float*)d_ws + 131136;
        float* h2   = (float*)d_out;

        k_detect<<<1, 256, 0, stream>>>(ei, flag);
        k_deg_init_f<<<(N_NODES + 255) / 256, 256, 0, stream>>>(dinv);
        k_deg_count_f<<<(N_EDGES + 255) / 256, 256, 0, stream>>>(ei, flag, dinv);
        k_dinv_f<<<(N_NODES + 255) / 256, 256, 0, stream>>>(dinv);
        k_selfinit_x<<<(N_NODES * (IN_DIM / 4) + 255) / 256, 256, 0, stream>>>(
            (const float4*)x, dinv, (float4*)big);
        k_scatter_x<<<(N_EDGES * 32 + 255) / 256, 256, 0, stream>>>(
            (const float4*)x, dinv, ei, flag, big);
        k_gemm1<<<1024, 256, 0, stream>>>(big, (const float4*)W1, b1);
        k_gemm2<<<1024, 256, 0, stream>>>(big, (const float2*)W2, h2, OUT_DIM);
        k_selfinit_h2<<<(N_NODES * (OUT_DIM / 4) + 255) / 256, 256, 0, stream>>>(
            (const float4*)h2, dinv, (float4*)big);
        k_scatter_h2<<<(N_EDGES * 16 + 255) / 256, 256, 0, stream>>>(
            (const float4*)h2, dinv, ei, flag, big);
        k_final<<<(N_NODES * (OUT_DIM / 4) + 255) / 256, 256, 0, stream>>>(
            (const float4*)big, b2, (float4*)d_out);
    }
}

// Round 5
// 487.049 us; speedup vs baseline: 9.1123x; 1.4090x over previous
//
#include <hip/hip_runtime.h>
#include <hip/hip_bf16.h>

#define N_NODES 100000
#define N_EDGES 1600000
#define IN_DIM  128
#define HID_DIM 128
#define OUT_DIM 64
#define SCAN_CHUNK 1024
#define NBLK_SCAN ((N_NODES + SCAN_CHUNK - 1) / SCAN_CHUNK)  // 98

typedef __attribute__((ext_vector_type(8))) short short8;
typedef __attribute__((ext_vector_type(4))) float floatx4;

__device__ __forceinline__ float eluf(float x) { return x > 0.0f ? x : expm1f(x); }
__device__ __forceinline__ unsigned short bfbits(float f) {
    union { __hip_bfloat16 h; unsigned short u; } c; c.h = __float2bfloat16(f); return c.u;
}
__device__ __forceinline__ unsigned packbf(float a, float b) {
    return (unsigned)bfbits(a) | ((unsigned)bfbits(b) << 16);
}
__device__ __forceinline__ float lo16(unsigned u) { return __uint_as_float(u << 16); }
__device__ __forceinline__ float hi16(unsigned u) { return __uint_as_float(u & 0xffff0000u); }

// ---- edge_index dtype probe: int64 data has all-zero odd int32 words ----
__global__ void k_detect(const int* __restrict__ ei, int* __restrict__ flag) {
    __shared__ int acc;
    if (threadIdx.x == 0) acc = 0;
    __syncthreads();
    int v = 0;
    for (int e = threadIdx.x; e < 1024; e += 256) v |= ei[2 * e + 1];
    atomicOr(&acc, v);
    __syncthreads();
    if (threadIdx.x == 0) flag[0] = (acc == 0) ? 1 : 0;
}
__device__ __forceinline__ int esrc(const int* ei, int e, int is64) {
    return is64 ? ei[2 * e] : ei[e];
}
__device__ __forceinline__ int edst(const int* ei, int e, int is64) {
    return is64 ? ei[2 * (N_EDGES + e)] : ei[N_EDGES + e];
}

// =================== CSR build ===================
__global__ void k_zero_int(int* __restrict__ p, int n) {
    int i = blockIdx.x * blockDim.x + threadIdx.x;
    if (i < n) p[i] = 0;
}
__global__ void k_deg_count_i(const int* __restrict__ ei, const int* __restrict__ flag,
                              int* __restrict__ deg) {
    int e = blockIdx.x * blockDim.x + threadIdx.x;
    if (e < N_EDGES) atomicAdd(&deg[edst(ei, e, flag[0])], 1);
}
__global__ void k_dinv_i(const int* __restrict__ deg, float* __restrict__ dinv) {
    int i = blockIdx.x * blockDim.x + threadIdx.x;
    if (i < N_NODES) dinv[i] = rsqrtf((float)(deg[i] + 1));  // +1 self-loop
}
__global__ void k_scan1(const int* __restrict__ deg, int* __restrict__ rowStart,
                        int* __restrict__ bsum) {
    __shared__ int sd[256];
    int t = threadIdx.x, blk = blockIdx.x;
    int i0 = blk * SCAN_CHUNK + t * 4;
    int d0 = (i0 + 0 < N_NODES) ? deg[i0 + 0] : 0;
    int d1 = (i0 + 1 < N_NODES) ? deg[i0 + 1] : 0;
    int d2 = (i0 + 2 < N_NODES) ? deg[i0 + 2] : 0;
    int d3 = (i0 + 3 < N_NODES) ? deg[i0 + 3] : 0;
    int s4 = d0 + d1 + d2 + d3;
    sd[t] = s4;
    __syncthreads();
    int acc = s4;
    for (int off = 1; off < 256; off <<= 1) {
        int v = (t >= off) ? sd[t - off] : 0;
        __syncthreads();
        acc += v; sd[t] = acc;
        __syncthreads();
    }
    int excl = acc - s4;
    if (i0 + 0 < N_NODES) rowStart[i0 + 0] = excl;
    if (i0 + 1 < N_NODES) rowStart[i0 + 1] = excl + d0;
    if (i0 + 2 < N_NODES) rowStart[i0 + 2] = excl + d0 + d1;
    if (i0 + 3 < N_NODES) rowStart[i0 + 3] = excl + d0 + d1 + d2;
    if (t == 255) bsum[blk] = acc;
}
__global__ void k_scan2(int* __restrict__ bsum, int* __restrict__ rowStartN) {
    int run = 0;
    for (int b = 0; b < NBLK_SCAN; b++) { int v = bsum[b]; bsum[b] = run; run += v; }
    rowStartN[0] = run;
}
__global__ void k_scan3(int* __restrict__ rowStart, const int* __restrict__ bsum) {
    int i = blockIdx.x * blockDim.x + threadIdx.x;
    if (i < N_NODES) rowStart[i] += bsum[i >> 10];
}
__global__ void k_fill(const int* __restrict__ ei, const int* __restrict__ flag,
                       const int* __restrict__ rowStart, int* __restrict__ cursor,
                       int* __restrict__ csr) {
    int e = blockIdx.x * blockDim.x + threadIdx.x;
    if (e >= N_EDGES) return;
    int is64 = flag[0];
    int s = esrc(ei, e, is64), d = edst(ei, e, is64);
    int pos = atomicAdd(&cursor[d], 1);
    csr[rowStart[d] + pos] = s;
}

// =================== x -> bf16 cast ===================
__global__ void k_cast_x(const float4* __restrict__ x4, uint2* __restrict__ xb) {
    int i = blockIdx.x * blockDim.x + threadIdx.x;
    if (i >= N_NODES * (IN_DIM / 4)) return;
    float4 v = x4[i];
    uint2 o = { packbf(v.x, v.y), packbf(v.z, v.w) };
    xb[i] = o;
}

// =================== pull aggregation (bf16 rows, fp32 accum) ===================
// one wave per node; lane = u32 (2 cols) of the 128-wide bf16 row
__launch_bounds__(256)
__global__ void k_gather1(const unsigned* __restrict__ xb, const float* __restrict__ dinv,
                          const int* __restrict__ row, const int* __restrict__ csr,
                          unsigned* __restrict__ agg) {
    int w = (blockIdx.x * blockDim.x + threadIdx.x) >> 6;
    int lane = threadIdx.x & 63;
    if (w >= N_NODES) return;
    int beg = row[w], end = row[w + 1];
    float dd = dinv[w];
    unsigned sv = xb[w * 64 + lane];
    float ax = lo16(sv) * dd, ay = hi16(sv) * dd;
    int j = beg;
    for (; j + 2 <= end; j += 2) {
        int s0 = csr[j], s1 = csr[j + 1];
        float w0 = dinv[s0], w1 = dinv[s1];
        unsigned u0 = xb[s0 * 64 + lane];
        unsigned u1 = xb[s1 * 64 + lane];
        ax += lo16(u0) * w0 + lo16(u1) * w1;
        ay += hi16(u0) * w0 + hi16(u1) * w1;
    }
    if (j < end) {
        int s0 = csr[j]; float w0 = dinv[s0];
        unsigned u0 = xb[s0 * 64 + lane];
        ax += lo16(u0) * w0; ay += hi16(u0) * w0;
    }
    agg[w * 64 + lane] = packbf(ax * dd, ay * dd);
}

// one HALF-wave per node over h2 (64 bf16 cols = 32 u32); fused bias+ELU -> fp32 out
__launch_bounds__(256)
__global__ void k_gather2(const unsigned* __restrict__ h2, const float* __restrict__ dinv,
                          const int* __restrict__ row, const int* __restrict__ csr,
                          const float* __restrict__ b2, float* __restrict__ out) {
    int w = (blockIdx.x * blockDim.x + threadIdx.x) >> 5;
    int p = threadIdx.x & 31;
    if (w >= N_NODES) return;
    float2 bias = *(const float2*)(b2 + 2 * p);
    int beg = row[w], end = row[w + 1];
    float dd = dinv[w];
    unsigned sv = h2[w * 32 + p];
    float ax = lo16(sv) * dd, ay = hi16(sv) * dd;
    int j = beg;
    for (; j + 2 <= end; j += 2) {
        int s0 = csr[j], s1 = csr[j + 1];
        float w0 = dinv[s0], w1 = dinv[s1];
        unsigned u0 = h2[s0 * 32 + p];
        unsigned u1 = h2[s1 * 32 + p];
        ax += lo16(u0) * w0 + lo16(u1) * w1;
        ay += hi16(u0) * w0 + hi16(u1) * w1;
    }
    if (j < end) {
        int s0 = csr[j]; float w0 = dinv[s0];
        unsigned u0 = h2[s0 * 32 + p];
        ax += lo16(u0) * w0; ay += hi16(u0) * w0;
    }
    ax *= dd; ay *= dd;
    float2 r = { eluf(ax + bias.x), eluf(ay + bias.y) };
    *(float2*)(out + w * OUT_DIM + 2 * p) = r;
}

// =================== MFMA GEMMs (transposed orientation) ===================
// D = W^T-tile (A) x node-rows^T (B) => lane owns 4 consecutive cols of 1 node row.
// A-frag: lane l: W[k0+(l>>4)*8+j][ct*16+(l&15)]  (packed to LDS)
// B-frag: lane l: rows[rbase+(l&15)][k0+(l>>4)*8+j]  (16B contiguous from global)
// C/D   : lane l, reg i: h[rbase+(l&15)][ct*16+(l>>4)*4+i]

// h1 = elu(aggx @ W1 + b1), IN-PLACE on agg (wave reads its 16 rows fully before storing)
__launch_bounds__(256)
__global__ void k_gemm1_mfma(unsigned* __restrict__ agg, const float* __restrict__ W1,
                             const float* __restrict__ b1, int nblk) {
    __shared__ short w1p[4][8][64][8];  // [kk][ct][lane][j], 32 KB
    int t = threadIdx.x;
    for (int idx = t; idx < 8192; idx += 256) {  // u32 units
        int j2 = idx & 3, l = (idx >> 2) & 63, ct = (idx >> 8) & 7, kk = idx >> 11;
        int k = kk * 32 + (l >> 4) * 8 + j2 * 2;
        int c = ct * 16 + (l & 15);
        ((unsigned*)w1p)[idx] = packbf(W1[k * HID_DIM + c], W1[(k + 1) * HID_DIM + c]);
    }
    int lane = t & 63, wave = t >> 6;
    int q = lane >> 4, m = lane & 15;
    floatx4 bias[8];
#pragma unroll
    for (int ct = 0; ct < 8; ct++) bias[ct] = *(const floatx4*)(b1 + ct * 16 + q * 4);
    __syncthreads();
    for (int blk = blockIdx.x * 4 + wave; blk < nblk; blk += gridDim.x * 4) {
        int r = blk * 16 + m;
        const short8* arow = (const short8*)(agg + r * 64);
        short8 bfr[4];
#pragma unroll
        for (int kk = 0; kk < 4; kk++) bfr[kk] = arow[kk * 4 + q];
        floatx4 acc[8];
#pragma unroll
        for (int ct = 0; ct < 8; ct++) acc[ct] = (floatx4)0.0f;
#pragma unroll
        for (int kk = 0; kk < 4; kk++)
#pragma unroll
            for (int ct = 0; ct < 8; ct++) {
                short8 af = *(const short8*)(&w1p[kk][ct][lane][0]);
                acc[ct] = __builtin_amdgcn_mfma_f32_16x16x32_bf16(af, bfr[kk], acc[ct], 0, 0, 0);
            }
        unsigned* hrow = agg + r * 64;
#pragma unroll
        for (int ct = 0; ct < 8; ct++) {
            uint2 o;
            o.x = packbf(eluf(acc[ct][0] + bias[ct][0]), eluf(acc[ct][1] + bias[ct][1]));
            o.y = packbf(eluf(acc[ct][2] + bias[ct][2]), eluf(acc[ct][3] + bias[ct][3]));
            *(uint2*)(hrow + ct * 8 + q * 2) = o;
        }
    }
}

// h2 = h1 @ W2 (bias/elu deferred to after aggregation), bf16 out
__launch_bounds__(256)
__global__ void k_gemm2_mfma(const unsigned* __restrict__ h1, const float* __restrict__ W2,
                             unsigned* __restrict__ h2, int nblk) {
    __shared__ short w2p[4][4][64][8];  // 16 KB
    int t = threadIdx.x;
    for (int idx = t; idx < 4096; idx += 256) {
        int j2 = idx & 3, l = (idx >> 2) & 63, ct = (idx >> 8) & 3, kk = idx >> 10;
        int k = kk * 32 + (l >> 4) * 8 + j2 * 2;
        int c = ct * 16 + (l & 15);
        ((unsigned*)w2p)[idx] = packbf(W2[k * OUT_DIM + c], W2[(k + 1) * OUT_DIM + c]);
    }
    int lane = t & 63, wave = t >> 6;
    int q = lane >> 4, m = lane & 15;
    __syncthreads();
    for (int blk = blockIdx.x * 4 + wave; blk < nblk; blk += gridDim.x * 4) {
        int r = blk * 16 + m;
        const short8* arow = (const short8*)(h1 + r * 64);
        short8 bfr[4];
#pragma unroll
        for (int kk = 0; kk < 4; kk++) bfr[kk] = arow[kk * 4 + q];
        floatx4 acc[4];
#pragma unroll
        for (int ct = 0; ct < 4; ct++) acc[ct] = (floatx4)0.0f;
#pragma unroll
        for (int kk = 0; kk < 4; kk++)
#pragma unroll
            for (int ct = 0; ct < 4; ct++) {
                short8 af = *(const short8*)(&w2p[kk][ct][lane][0]);
                acc[ct] = __builtin_amdgcn_mfma_f32_16x16x32_bf16(af, bfr[kk], acc[ct], 0, 0, 0);
            }
        unsigned* orow = h2 + r * 32;
#pragma unroll
        for (int ct = 0; ct < 4; ct++) {
            uint2 o;
            o.x = packbf(acc[ct][0], acc[ct][1]);
            o.y = packbf(acc[ct][2], acc[ct][3]);
            *(uint2*)(orow + ct * 8 + q * 2) = o;
        }
    }
}

extern "C" void kernel_launch(void* const* d_in, const int* in_sizes, int n_in,
                              void* d_out, int out_size, void* d_ws, size_t ws_size,
                              hipStream_t stream) {
    const float* x  = (const float*)d_in[0];
    const int*   ei = (const int*)d_in[1];
    const float* W1 = (const float*)d_in[2];
    const float* b1 = (const float*)d_in[3];
    const float* W2 = (const float*)d_in[4];
    const float* b2 = (const float*)d_in[5];

    // ---- layout (u32 units) ----
    const size_t OFF_FLAG = 0, OFF_DEG = 16, OFF_ROW = 100016, OFF_BSUM = 200032,
                 OFF_CSR = 200192, OFF_DINV = 1800192,
                 OFF_XB = 1900288,          // x bf16 [N,128] (6.4M u32); later h2 bf16 [N,64]
                 OFF_AGG = 8300288;         // aggx bf16 [N,128] -> h1 in place (6.4M u32)
    const size_t needed = (OFF_AGG + 6400000) * 4;  // 58,801,152 B (== round-4 footprint)
    if (ws_size < needed) return;  // canary: zero output, finite absmax

    int*      flag = (int*)d_ws + OFF_FLAG;
    int*      deg  = (int*)d_ws + OFF_DEG;   // reused as cursor
    int*      row  = (int*)d_ws + OFF_ROW;
    int*      bsum = (int*)d_ws + OFF_BSUM;
    int*      csr  = (int*)d_ws + OFF_CSR;
    float*    dinv = (float*)d_ws + OFF_DINV;
    unsigned* xb   = (unsigned*)d_ws + OFF_XB;
    unsigned* agg  = (unsigned*)d_ws + OFF_AGG;

    // CSR build
    k_detect<<<1, 256, 0, stream>>>(ei, flag);
    k_zero_int<<<(N_NODES + 255) / 256, 256, 0, stream>>>(deg, N_NODES);
    k_deg_count_i<<<(N_EDGES + 255) / 256, 256, 0, stream>>>(ei, flag, deg);
    k_dinv_i<<<(N_NODES + 255) / 256, 256, 0, stream>>>(deg, dinv);
    k_scan1<<<NBLK_SCAN, 256, 0, stream>>>(deg, row, bsum);
    k_scan2<<<1, 1, 0, stream>>>(bsum, row + N_NODES);
    k_scan3<<<(N_NODES + 255) / 256, 256, 0, stream>>>(row, bsum);
    k_zero_int<<<(N_NODES + 255) / 256, 256, 0, stream>>>(deg, N_NODES);
    k_fill<<<(N_EDGES + 255) / 256, 256, 0, stream>>>(ei, flag, row, deg, csr);

    // cast x to bf16
    k_cast_x<<<(N_NODES * (IN_DIM / 4) + 255) / 256, 256, 0, stream>>>(
        (const float4*)x, (uint2*)xb);

    // layer 1: pull-aggregate xb -> agg (bf16), MFMA GEMM in place (+bias+ELU)
    k_gather1<<<(N_NODES * 64 + 255) / 256, 256, 0, stream>>>(xb, dinv, row, csr, agg);
    k_gemm1_mfma<<<1024, 256, 0, stream>>>(agg, W1, b1, N_NODES / 16);

    // layer 2: MFMA GEMM h1 -> h2 (bf16, reuses xb slot), pull-aggregate + bias + ELU -> out
    k_gemm2_mfma<<<1024, 256, 0, stream>>>(agg, W2, xb, N_NODES / 16);
    k_gather2<<<(N_NODES * 32 + 255) / 256, 256, 0, stream>>>(
        xb, dinv, row, csr, b2, (float*)d_out);
}

// Round 6
// 366.120 us; speedup vs baseline: 12.1221x; 1.3303x over previous
//
#include <hip/hip_runtime.h>
#include <hip/hip_bf16.h>

#define N_NODES 100000
#define N_EDGES 1600000
#define IN_DIM  128
#define HID_DIM 128
#define OUT_DIM 64
#define SCAN_CHUNK 1024
#define NBLK_SCAN ((N_NODES + SCAN_CHUNK - 1) / SCAN_CHUNK)  // 98

typedef __attribute__((ext_vector_type(8))) short short8;
typedef __attribute__((ext_vector_type(4))) float floatx4;

__device__ __forceinline__ float eluf(float x) { return x > 0.0f ? x : expm1f(x); }
__device__ __forceinline__ unsigned short bfbits(float f) {
    union { __hip_bfloat16 h; unsigned short u; } c; c.h = __float2bfloat16(f); return c.u;
}
__device__ __forceinline__ unsigned packbf(float a, float b) {
    return (unsigned)bfbits(a) | ((unsigned)bfbits(b) << 16);
}
__device__ __forceinline__ float lo16(unsigned u) { return __uint_as_float(u << 16); }
__device__ __forceinline__ float hi16(unsigned u) { return __uint_as_float(u & 0xffff0000u); }

// ---- edge_index dtype probe: int64 data has all-zero odd int32 words ----
__global__ void k_detect(const int* __restrict__ ei, int* __restrict__ flag) {
    __shared__ int acc;
    if (threadIdx.x == 0) acc = 0;
    __syncthreads();
    int v = 0;
    for (int e = threadIdx.x; e < 1024; e += 256) v |= ei[2 * e + 1];
    atomicOr(&acc, v);
    __syncthreads();
    if (threadIdx.x == 0) flag[0] = (acc == 0) ? 1 : 0;
}
__device__ __forceinline__ int esrc(const int* ei, int e, int is64) {
    return is64 ? ei[2 * e] : ei[e];
}
__device__ __forceinline__ int edst(const int* ei, int e, int is64) {
    return is64 ? ei[2 * (N_EDGES + e)] : ei[N_EDGES + e];
}

// =================== CSR build ===================
__global__ void k_zero_int(int* __restrict__ p, int n) {
    int i = blockIdx.x * blockDim.x + threadIdx.x;
    if (i < n) p[i] = 0;
}
// degree count + per-edge slot record (the ONLY atomic pass)
__global__ void k_deg_pos(const int* __restrict__ ei, const int* __restrict__ flag,
                          int* __restrict__ deg, int* __restrict__ epos) {
    int e = blockIdx.x * blockDim.x + threadIdx.x;
    if (e >= N_EDGES) return;
    int d = edst(ei, e, flag[0]);
    epos[e] = atomicAdd(&deg[d], 1);
}
// scan over degrees (also emits dinv = rsqrt(deg+1))
__global__ void k_scan1(const int* __restrict__ deg, int* __restrict__ rowStart,
                        int* __restrict__ bsum, float* __restrict__ dinv) {
    __shared__ int sd[256];
    int t = threadIdx.x, blk = blockIdx.x;
    int i0 = blk * SCAN_CHUNK + t * 4;
    int d0 = (i0 + 0 < N_NODES) ? deg[i0 + 0] : 0;
    int d1 = (i0 + 1 < N_NODES) ? deg[i0 + 1] : 0;
    int d2 = (i0 + 2 < N_NODES) ? deg[i0 + 2] : 0;
    int d3 = (i0 + 3 < N_NODES) ? deg[i0 + 3] : 0;
    if (i0 + 0 < N_NODES) dinv[i0 + 0] = rsqrtf((float)(d0 + 1));
    if (i0 + 1 < N_NODES) dinv[i0 + 1] = rsqrtf((float)(d1 + 1));
    if (i0 + 2 < N_NODES) dinv[i0 + 2] = rsqrtf((float)(d2 + 1));
    if (i0 + 3 < N_NODES) dinv[i0 + 3] = rsqrtf((float)(d3 + 1));
    int s4 = d0 + d1 + d2 + d3;
    sd[t] = s4;
    __syncthreads();
    int acc = s4;
    for (int off = 1; off < 256; off <<= 1) {
        int v = (t >= off) ? sd[t - off] : 0;
        __syncthreads();
        acc += v; sd[t] = acc;
        __syncthreads();
    }
    int excl = acc - s4;
    if (i0 + 0 < N_NODES) rowStart[i0 + 0] = excl;
    if (i0 + 1 < N_NODES) rowStart[i0 + 1] = excl + d0;
    if (i0 + 2 < N_NODES) rowStart[i0 + 2] = excl + d0 + d1;
    if (i0 + 3 < N_NODES) rowStart[i0 + 3] = excl + d0 + d1 + d2;
    if (t == 255) bsum[blk] = acc;
}
__global__ void k_scan2(int* __restrict__ bsum, int* __restrict__ rowStartN) {
    int run = 0;
    for (int b = 0; b < NBLK_SCAN; b++) { int v = bsum[b]; bsum[b] = run; run += v; }
    rowStartN[0] = run;
}
__global__ void k_scan3(int* __restrict__ rowStart, const int* __restrict__ bsum) {
    int i = blockIdx.x * blockDim.x + threadIdx.x;
    if (i < N_NODES) rowStart[i] += bsum[i >> 10];
}
// atomic-free fill: slot was precomputed in k_deg_pos
__global__ void k_fill(const int* __restrict__ ei, const int* __restrict__ flag,
                       const int* __restrict__ rowStart, const int* __restrict__ epos,
                       int* __restrict__ csr) {
    int e = blockIdx.x * blockDim.x + threadIdx.x;
    if (e >= N_EDGES) return;
    int is64 = flag[0];
    int s = esrc(ei, e, is64), d = edst(ei, e, is64);
    csr[rowStart[d] + epos[e]] = s;
}

// =================== x -> bf16 cast ===================
__global__ void k_cast_x(const float4* __restrict__ x4, uint2* __restrict__ xb) {
    int i = blockIdx.x * blockDim.x + threadIdx.x;
    if (i >= N_NODES * (IN_DIM / 4)) return;
    float4 v = x4[i];
    uint2 o = { packbf(v.x, v.y), packbf(v.z, v.w) };
    xb[i] = o;
}

// =================== pull aggregation (bf16 rows, fp32 accum) ===================
// one wave per node; lane = u32 (2 cols) of the 128-wide bf16 row
__launch_bounds__(256)
__global__ void k_gather1(const unsigned* __restrict__ xb, const float* __restrict__ dinv,
                          const int* __restrict__ row, const int* __restrict__ csr,
                          unsigned* __restrict__ agg) {
    int w = (blockIdx.x * blockDim.x + threadIdx.x) >> 6;
    int lane = threadIdx.x & 63;
    if (w >= N_NODES) return;
    int beg = row[w], end = row[w + 1];
    float dd = dinv[w];
    unsigned sv = xb[w * 64 + lane];
    float ax = lo16(sv) * dd, ay = hi16(sv) * dd;
    int j = beg;
    for (; j + 4 <= end; j += 4) {
        int s0 = csr[j], s1 = csr[j + 1], s2 = csr[j + 2], s3 = csr[j + 3];
        float w0 = dinv[s0], w1 = dinv[s1], w2 = dinv[s2], w3 = dinv[s3];
        unsigned u0 = xb[s0 * 64 + lane];
        unsigned u1 = xb[s1 * 64 + lane];
        unsigned u2 = xb[s2 * 64 + lane];
        unsigned u3 = xb[s3 * 64 + lane];
        ax += lo16(u0) * w0 + lo16(u1) * w1 + lo16(u2) * w2 + lo16(u3) * w3;
        ay += hi16(u0) * w0 + hi16(u1) * w1 + hi16(u2) * w2 + hi16(u3) * w3;
    }
    for (; j < end; j++) {
        int s0 = csr[j]; float w0 = dinv[s0];
        unsigned u0 = xb[s0 * 64 + lane];
        ax += lo16(u0) * w0; ay += hi16(u0) * w0;
    }
    agg[w * 64 + lane] = packbf(ax * dd, ay * dd);
}

// one HALF-wave per node over h2 (64 bf16 cols = 32 u32); fused bias+ELU -> fp32 out
__launch_bounds__(256)
__global__ void k_gather2(const unsigned* __restrict__ h2, const float* __restrict__ dinv,
                          const int* __restrict__ row, const int* __restrict__ csr,
                          const float* __restrict__ b2, float* __restrict__ out) {
    int w = (blockIdx.x * blockDim.x + threadIdx.x) >> 5;
    int p = threadIdx.x & 31;
    if (w >= N_NODES) return;
    float2 bias = *(const float2*)(b2 + 2 * p);
    int beg = row[w], end = row[w + 1];
    float dd = dinv[w];
    unsigned sv = h2[w * 32 + p];
    float ax = lo16(sv) * dd, ay = hi16(sv) * dd;
    int j = beg;
    for (; j + 4 <= end; j += 4) {
        int s0 = csr[j], s1 = csr[j + 1], s2 = csr[j + 2], s3 = csr[j + 3];
        float w0 = dinv[s0], w1 = dinv[s1], w2 = dinv[s2], w3 = dinv[s3];
        unsigned u0 = h2[s0 * 32 + p];
        unsigned u1 = h2[s1 * 32 + p];
        unsigned u2 = h2[s2 * 32 + p];
        unsigned u3 = h2[s3 * 32 + p];
        ax += lo16(u0) * w0 + lo16(u1) * w1 + lo16(u2) * w2 + lo16(u3) * w3;
        ay += hi16(u0) * w0 + hi16(u1) * w1 + hi16(u2) * w2 + hi16(u3) * w3;
    }
    for (; j < end; j++) {
        int s0 = csr[j]; float w0 = dinv[s0];
        unsigned u0 = h2[s0 * 32 + p];
        ax += lo16(u0) * w0; ay += hi16(u0) * w0;
    }
    ax *= dd; ay *= dd;
    float2 r = { eluf(ax + bias.x), eluf(ay + bias.y) };
    *(float2*)(out + w * OUT_DIM + 2 * p) = r;
}

// =================== MFMA GEMMs (transposed orientation) ===================
// h1 = elu(aggx @ W1 + b1), IN-PLACE on agg (wave reads its 16 rows fully before storing)
__launch_bounds__(256)
__global__ void k_gemm1_mfma(unsigned* __restrict__ agg, const float* __restrict__ W1,
                             const float* __restrict__ b1, int nblk) {
    __shared__ short w1p[4][8][64][8];  // [kk][ct][lane][j], 32 KB
    int t = threadIdx.x;
    for (int idx = t; idx < 8192; idx += 256) {  // u32 units
        int j2 = idx & 3, l = (idx >> 2) & 63, ct = (idx >> 8) & 7, kk = idx >> 11;
        int k = kk * 32 + (l >> 4) * 8 + j2 * 2;
        int c = ct * 16 + (l & 15);
        ((unsigned*)w1p)[idx] = packbf(W1[k * HID_DIM + c], W1[(k + 1) * HID_DIM + c]);
    }
    int lane = t & 63, wave = t >> 6;
    int q = lane >> 4, m = lane & 15;
    floatx4 bias[8];
#pragma unroll
    for (int ct = 0; ct < 8; ct++) bias[ct] = *(const floatx4*)(b1 + ct * 16 + q * 4);
    __syncthreads();
    for (int blk = blockIdx.x * 4 + wave; blk < nblk; blk += gridDim.x * 4) {
        int r = blk * 16 + m;
        const short8* arow = (const short8*)(agg + r * 64);
        short8 bfr[4];
#pragma unroll
        for (int kk = 0; kk < 4; kk++) bfr[kk] = arow[kk * 4 + q];
        floatx4 acc[8];
#pragma unroll
        for (int ct = 0; ct < 8; ct++) acc[ct] = (floatx4)0.0f;
#pragma unroll
        for (int kk = 0; kk < 4; kk++)
#pragma unroll
            for (int ct = 0; ct < 8; ct++) {
                short8 af = *(const short8*)(&w1p[kk][ct][lane][0]);
                acc[ct] = __builtin_amdgcn_mfma_f32_16x16x32_bf16(af, bfr[kk], acc[ct], 0, 0, 0);
            }
        unsigned* hrow = agg + r * 64;
#pragma unroll
        for (int ct = 0; ct < 8; ct++) {
            uint2 o;
            o.x = packbf(eluf(acc[ct][0] + bias[ct][0]), eluf(acc[ct][1] + bias[ct][1]));
            o.y = packbf(eluf(acc[ct][2] + bias[ct][2]), eluf(acc[ct][3] + bias[ct][3]));
            *(uint2*)(hrow + ct * 8 + q * 2) = o;
        }
    }
}

// h2 = h1 @ W2 (bias/elu deferred to after aggregation), bf16 out
__launch_bounds__(256)
__global__ void k_gemm2_mfma(const unsigned* __restrict__ h1, const float* __restrict__ W2,
                             unsigned* __restrict__ h2, int nblk) {
    __shared__ short w2p[4][4][64][8];  // 16 KB
    int t = threadIdx.x;
    for (int idx = t; idx < 4096; idx += 256) {
        int j2 = idx & 3, l = (idx >> 2) & 63, ct = (idx >> 8) & 3, kk = idx >> 10;
        int k = kk * 32 + (l >> 4) * 8 + j2 * 2;
        int c = ct * 16 + (l & 15);
        ((unsigned*)w2p)[idx] = packbf(W2[k * OUT_DIM + c], W2[(k + 1) * OUT_DIM + c]);
    }
    int lane = t & 63, wave = t >> 6;
    int q = lane >> 4, m = lane & 15;
    __syncthreads();
    for (int blk = blockIdx.x * 4 + wave; blk < nblk; blk += gridDim.x * 4) {
        int r = blk * 16 + m;
        const short8* arow = (const short8*)(h1 + r * 64);
        short8 bfr[4];
#pragma unroll
        for (int kk = 0; kk < 4; kk++) bfr[kk] = arow[kk * 4 + q];
        floatx4 acc[4];
#pragma unroll
        for (int ct = 0; ct < 4; ct++) acc[ct] = (floatx4)0.0f;
#pragma unroll
        for (int kk = 0; kk < 4; kk++)
#pragma unroll
            for (int ct = 0; ct < 4; ct++) {
                short8 af = *(const short8*)(&w2p[kk][ct][lane][0]);
                acc[ct] = __builtin_amdgcn_mfma_f32_16x16x32_bf16(af, bfr[kk], acc[ct], 0, 0, 0);
            }
        unsigned* orow = h2 + r * 32;
#pragma unroll
        for (int ct = 0; ct < 4; ct++) {
            uint2 o;
            o.x = packbf(acc[ct][0], acc[ct][1]);
            o.y = packbf(acc[ct][2], acc[ct][3]);
            *(uint2*)(orow + ct * 8 + q * 2) = o;
        }
    }
}

extern "C" void kernel_launch(void* const* d_in, const int* in_sizes, int n_in,
                              void* d_out, int out_size, void* d_ws, size_t ws_size,
                              hipStream_t stream) {
    const float* x  = (const float*)d_in[0];
    const int*   ei = (const int*)d_in[1];
    const float* W1 = (const float*)d_in[2];
    const float* b1 = (const float*)d_in[3];
    const float* W2 = (const float*)d_in[4];
    const float* b2 = (const float*)d_in[5];

    // ---- layout (u32 units) ----
    const size_t OFF_FLAG = 0, OFF_DEG = 16, OFF_ROW = 100016, OFF_BSUM = 200032,
                 OFF_CSR = 200192, OFF_DINV = 1800192,
                 OFF_XB = 1900288,          // x bf16 [N,128] (6.4M u32); later h2 bf16 [N,64]
                 OFF_AGG = 8300288;         // epos during CSR build; then aggx bf16 -> h1
    const size_t needed = (OFF_AGG + 6400000) * 4;  // 58,801,152 B (== round-4/5 footprint)
    if (ws_size < needed) return;  // canary: zero output, finite absmax

    int*      flag = (int*)d_ws + OFF_FLAG;
    int*      deg  = (int*)d_ws + OFF_DEG;
    int*      row  = (int*)d_ws + OFF_ROW;
    int*      bsum = (int*)d_ws + OFF_BSUM;
    int*      csr  = (int*)d_ws + OFF_CSR;
    float*    dinv = (float*)d_ws + OFF_DINV;
    unsigned* xb   = (unsigned*)d_ws + OFF_XB;
    unsigned* agg  = (unsigned*)d_ws + OFF_AGG;
    int*      epos = (int*)agg;  // dead slot during CSR build (1.6M of 6.4M u32)

    // CSR build (single atomic pass)
    k_detect<<<1, 256, 0, stream>>>(ei, flag);
    k_zero_int<<<(N_NODES + 255) / 256, 256, 0, stream>>>(deg, N_NODES);
    k_deg_pos<<<(N_EDGES + 255) / 256, 256, 0, stream>>>(ei, flag, deg, epos);
    k_scan1<<<NBLK_SCAN, 256, 0, stream>>>(deg, row, bsum, dinv);
    k_scan2<<<1, 1, 0, stream>>>(bsum, row + N_NODES);
    k_scan3<<<(N_NODES + 255) / 256, 256, 0, stream>>>(row, bsum);
    k_fill<<<(N_EDGES + 255) / 256, 256, 0, stream>>>(ei, flag, row, epos, csr);

    // cast x to bf16
    k_cast_x<<<(N_NODES * (IN_DIM / 4) + 255) / 256, 256, 0, stream>>>(
        (const float4*)x, (uint2*)xb);

    // layer 1: pull-aggregate xb -> agg (bf16), MFMA GEMM in place (+bias+ELU)
    k_gather1<<<(N_NODES * 64 + 255) / 256, 256, 0, stream>>>(xb, dinv, row, csr, agg);
    k_gemm1_mfma<<<1024, 256, 0, stream>>>(agg, W1, b1, N_NODES / 16);

    // layer 2: MFMA GEMM h1 -> h2 (bf16, reuses xb slot), pull-aggregate + bias + ELU -> out
    k_gemm2_mfma<<<1024, 256, 0, stream>>>(agg, W2, xb, N_NODES / 16);
    k_gather2<<<(N_NODES * 32 + 255) / 256, 256, 0, stream>>>(
        xb, dinv, row, csr, b2, (float*)d_out);
}

// Round 7
// 350.568 us; speedup vs baseline: 12.6598x; 1.0444x over previous
//
#include <hip/hip_runtime.h>
#include <hip/hip_bf16.h>

#define N_NODES 100000
#define N_EDGES 1600000
#define IN_DIM  128
#define HID_DIM 128
#define OUT_DIM 64
#define SCAN_CHUNK 1024
#define NBLK_SCAN ((N_NODES + SCAN_CHUNK - 1) / SCAN_CHUNK)  // 98

typedef __attribute__((ext_vector_type(8))) short short8;
typedef __attribute__((ext_vector_type(4))) float floatx4;

__device__ __forceinline__ float eluf(float x) { return x > 0.0f ? x : expm1f(x); }
__device__ __forceinline__ unsigned short bfbits(float f) {
    union { __hip_bfloat16 h; unsigned short u; } c; c.h = __float2bfloat16(f); return c.u;
}
__device__ __forceinline__ unsigned packbf(float a, float b) {
    return (unsigned)bfbits(a) | ((unsigned)bfbits(b) << 16);
}
__device__ __forceinline__ float lo16(unsigned u) { return __uint_as_float(u << 16); }
__device__ __forceinline__ float hi16(unsigned u) { return __uint_as_float(u & 0xffff0000u); }

// ---- edge_index dtype probe: int64 data has all-zero odd int32 words ----
__global__ void k_detect(const int* __restrict__ ei, int* __restrict__ flag) {
    __shared__ int acc;
    if (threadIdx.x == 0) acc = 0;
    __syncthreads();
    int v = 0;
    for (int e = threadIdx.x; e < 1024; e += 256) v |= ei[2 * e + 1];
    atomicOr(&acc, v);
    __syncthreads();
    if (threadIdx.x == 0) flag[0] = (acc == 0) ? 1 : 0;
}
__device__ __forceinline__ int esrc(const int* ei, int e, int is64) {
    return is64 ? ei[2 * e] : ei[e];
}
__device__ __forceinline__ int edst(const int* ei, int e, int is64) {
    return is64 ? ei[2 * (N_EDGES + e)] : ei[N_EDGES + e];
}

// =================== CSR build ===================
// degree count + per-edge slot record (the ONLY atomic pass)
__global__ void k_deg_pos(const int* __restrict__ ei, const int* __restrict__ flag,
                          int* __restrict__ deg, unsigned short* __restrict__ epos) {
    int e = blockIdx.x * blockDim.x + threadIdx.x;
    if (e >= N_EDGES) return;
    int d = edst(ei, e, flag[0]);
    epos[e] = (unsigned short)atomicAdd(&deg[d], 1);
}
// scan over degrees (also emits dinv = rsqrt(deg+1))
__global__ void k_scan1(const int* __restrict__ deg, int* __restrict__ rowStart,
                        int* __restrict__ bsum, float* __restrict__ dinv) {
    __shared__ int sd[256];
    int t = threadIdx.x, blk = blockIdx.x;
    int i0 = blk * SCAN_CHUNK + t * 4;
    int d0 = (i0 + 0 < N_NODES) ? deg[i0 + 0] : 0;
    int d1 = (i0 + 1 < N_NODES) ? deg[i0 + 1] : 0;
    int d2 = (i0 + 2 < N_NODES) ? deg[i0 + 2] : 0;
    int d3 = (i0 + 3 < N_NODES) ? deg[i0 + 3] : 0;
    if (i0 + 0 < N_NODES) dinv[i0 + 0] = rsqrtf((float)(d0 + 1));
    if (i0 + 1 < N_NODES) dinv[i0 + 1] = rsqrtf((float)(d1 + 1));
    if (i0 + 2 < N_NODES) dinv[i0 + 2] = rsqrtf((float)(d2 + 1));
    if (i0 + 3 < N_NODES) dinv[i0 + 3] = rsqrtf((float)(d3 + 1));
    int s4 = d0 + d1 + d2 + d3;
    sd[t] = s4;
    __syncthreads();
    int acc = s4;
    for (int off = 1; off < 256; off <<= 1) {
        int v = (t >= off) ? sd[t - off] : 0;
        __syncthreads();
        acc += v; sd[t] = acc;
        __syncthreads();
    }
    int excl = acc - s4;
    if (i0 + 0 < N_NODES) rowStart[i0 + 0] = excl;
    if (i0 + 1 < N_NODES) rowStart[i0 + 1] = excl + d0;
    if (i0 + 2 < N_NODES) rowStart[i0 + 2] = excl + d0 + d1;
    if (i0 + 3 < N_NODES) rowStart[i0 + 3] = excl + d0 + d1 + d2;
    if (t == 255) bsum[blk] = acc;
}
// parallel block-sum scan (98 values, one 128-thread block)
__global__ void k_scan2(int* __restrict__ bsum, int* __restrict__ rowStartN) {
    __shared__ int sd[128];
    int t = threadIdx.x;
    int v = (t < NBLK_SCAN) ? bsum[t] : 0;
    sd[t] = v;
    __syncthreads();
    int acc = v;
    for (int off = 1; off < 128; off <<= 1) {
        int u = (t >= off) ? sd[t - off] : 0;
        __syncthreads();
        acc += u; sd[t] = acc;
        __syncthreads();
    }
    if (t < NBLK_SCAN) bsum[t] = acc - v;      // exclusive
    if (t == NBLK_SCAN - 1) rowStartN[0] = acc; // total
}
__global__ void k_scan3(int* __restrict__ rowStart, const int* __restrict__ bsum) {
    int i = blockIdx.x * blockDim.x + threadIdx.x;
    if (i < N_NODES) rowStart[i] += bsum[i >> 10];
}
// atomic-free fill: slot was precomputed in k_deg_pos
__global__ void k_fill(const int* __restrict__ ei, const int* __restrict__ flag,
                       const int* __restrict__ rowStart, const unsigned short* __restrict__ epos,
                       int* __restrict__ csr) {
    int e = blockIdx.x * blockDim.x + threadIdx.x;
    if (e >= N_EDGES) return;
    int is64 = flag[0];
    int s = esrc(ei, e, is64), d = edst(ei, e, is64);
    csr[rowStart[d] + (int)epos[e]] = s;
}

// =================== x -> bf16 cast ===================
__global__ void k_cast_x(const float4* __restrict__ x4, uint2* __restrict__ xb) {
    int i = blockIdx.x * blockDim.x + threadIdx.x;
    if (i >= N_NODES * (IN_DIM / 4)) return;
    float4 v = x4[i];
    uint2 o = { packbf(v.x, v.y), packbf(v.z, v.w) };
    xb[i] = o;
}

// =================== pull aggregation (bf16 rows, fp32 accum, unroll-8) ===================
// one wave per node; lane = u32 (2 cols) of the 128-wide bf16 row
__launch_bounds__(256)
__global__ void k_gather1(const unsigned* __restrict__ xb, const float* __restrict__ dinv,
                          const int* __restrict__ row, const int* __restrict__ csr,
                          unsigned* __restrict__ agg) {
    int w = (blockIdx.x * blockDim.x + threadIdx.x) >> 6;
    int lane = threadIdx.x & 63;
    if (w >= N_NODES) return;
    int beg = row[w], end = row[w + 1];
    float dd = dinv[w];
    unsigned sv = xb[w * 64 + lane];
    float ax = lo16(sv) * dd, ay = hi16(sv) * dd;
    int j = beg;
    for (; j + 8 <= end; j += 8) {
        int s[8]; float wd[8]; unsigned u[8];
#pragma unroll
        for (int q = 0; q < 8; q++) s[q] = csr[j + q];
#pragma unroll
        for (int q = 0; q < 8; q++) wd[q] = dinv[s[q]];
#pragma unroll
        for (int q = 0; q < 8; q++) u[q] = xb[s[q] * 64 + lane];
#pragma unroll
        for (int q = 0; q < 8; q++) { ax += lo16(u[q]) * wd[q]; ay += hi16(u[q]) * wd[q]; }
    }
    for (; j + 2 <= end; j += 2) {
        int s0 = csr[j], s1 = csr[j + 1];
        float w0 = dinv[s0], w1 = dinv[s1];
        unsigned u0 = xb[s0 * 64 + lane];
        unsigned u1 = xb[s1 * 64 + lane];
        ax += lo16(u0) * w0 + lo16(u1) * w1;
        ay += hi16(u0) * w0 + hi16(u1) * w1;
    }
    if (j < end) {
        int s0 = csr[j]; float w0 = dinv[s0];
        unsigned u0 = xb[s0 * 64 + lane];
        ax += lo16(u0) * w0; ay += hi16(u0) * w0;
    }
    agg[w * 64 + lane] = packbf(ax * dd, ay * dd);
}

// one HALF-wave per node over h2 (64 bf16 cols = 32 u32); fused bias+ELU -> fp32 out
__launch_bounds__(256)
__global__ void k_gather2(const unsigned* __restrict__ h2, const float* __restrict__ dinv,
                          const int* __restrict__ row, const int* __restrict__ csr,
                          const float* __restrict__ b2, float* __restrict__ out) {
    int w = (blockIdx.x * blockDim.x + threadIdx.x) >> 5;
    int p = threadIdx.x & 31;
    if (w >= N_NODES) return;
    float2 bias = *(const float2*)(b2 + 2 * p);
    int beg = row[w], end = row[w + 1];
    float dd = dinv[w];
    unsigned sv = h2[w * 32 + p];
    float ax = lo16(sv) * dd, ay = hi16(sv) * dd;
    int j = beg;
    for (; j + 8 <= end; j += 8) {
        int s[8]; float wd[8]; unsigned u[8];
#pragma unroll
        for (int q = 0; q < 8; q++) s[q] = csr[j + q];
#pragma unroll
        for (int q = 0; q < 8; q++) wd[q] = dinv[s[q]];
#pragma unroll
        for (int q = 0; q < 8; q++) u[q] = h2[s[q] * 32 + p];
#pragma unroll
        for (int q = 0; q < 8; q++) { ax += lo16(u[q]) * wd[q]; ay += hi16(u[q]) * wd[q]; }
    }
    for (; j + 2 <= end; j += 2) {
        int s0 = csr[j], s1 = csr[j + 1];
        float w0 = dinv[s0], w1 = dinv[s1];
        unsigned u0 = h2[s0 * 32 + p];
        unsigned u1 = h2[s1 * 32 + p];
        ax += lo16(u0) * w0 + lo16(u1) * w1;
        ay += hi16(u0) * w0 + hi16(u1) * w1;
    }
    if (j < end) {
        int s0 = csr[j]; float w0 = dinv[s0];
        unsigned u0 = h2[s0 * 32 + p];
        ax += lo16(u0) * w0; ay += hi16(u0) * w0;
    }
    ax *= dd; ay *= dd;
    float2 r = { eluf(ax + bias.x), eluf(ay + bias.y) };
    *(float2*)(out + w * OUT_DIM + 2 * p) = r;
}

// =================== MFMA GEMMs (transposed orientation) ===================
// h1 = elu(aggx @ W1 + b1), IN-PLACE on agg (wave reads its 16 rows fully before storing)
__launch_bounds__(256)
__global__ void k_gemm1_mfma(unsigned* __restrict__ agg, const float* __restrict__ W1,
                             const float* __restrict__ b1, int nblk) {
    __shared__ short w1p[4][8][64][8];  // [kk][ct][lane][j], 32 KB
    int t = threadIdx.x;
    for (int idx = t; idx < 8192; idx += 256) {  // u32 units
        int j2 = idx & 3, l = (idx >> 2) & 63, ct = (idx >> 8) & 7, kk = idx >> 11;
        int k = kk * 32 + (l >> 4) * 8 + j2 * 2;
        int c = ct * 16 + (l & 15);
        ((unsigned*)w1p)[idx] = packbf(W1[k * HID_DIM + c], W1[(k + 1) * HID_DIM + c]);
    }
    int lane = t & 63, wave = t >> 6;
    int q = lane >> 4, m = lane & 15;
    floatx4 bias[8];
#pragma unroll
    for (int ct = 0; ct < 8; ct++) bias[ct] = *(const floatx4*)(b1 + ct * 16 + q * 4);
    __syncthreads();
    for (int blk = blockIdx.x * 4 + wave; blk < nblk; blk += gridDim.x * 4) {
        int r = blk * 16 + m;
        const short8* arow = (const short8*)(agg + r * 64);
        short8 bfr[4];
#pragma unroll
        for (int kk = 0; kk < 4; kk++) bfr[kk] = arow[kk * 4 + q];
        floatx4 acc[8];
#pragma unroll
        for (int ct = 0; ct < 8; ct++) acc[ct] = (floatx4)0.0f;
#pragma unroll
        for (int kk = 0; kk < 4; kk++)
#pragma unroll
            for (int ct = 0; ct < 8; ct++) {
                short8 af = *(const short8*)(&w1p[kk][ct][lane][0]);
                acc[ct] = __builtin_amdgcn_mfma_f32_16x16x32_bf16(af, bfr[kk], acc[ct], 0, 0, 0);
            }
        unsigned* hrow = agg + r * 64;
#pragma unroll
        for (int ct = 0; ct < 8; ct++) {
            uint2 o;
            o.x = packbf(eluf(acc[ct][0] + bias[ct][0]), eluf(acc[ct][1] + bias[ct][1]));
            o.y = packbf(eluf(acc[ct][2] + bias[ct][2]), eluf(acc[ct][3] + bias[ct][3]));
            *(uint2*)(hrow + ct * 8 + q * 2) = o;
        }
    }
}

// h2 = h1 @ W2 (bias/elu deferred to after aggregation), bf16 out
__launch_bounds__(256)
__global__ void k_gemm2_mfma(const unsigned* __restrict__ h1, const float* __restrict__ W2,
                             unsigned* __restrict__ h2, int nblk) {
    __shared__ short w2p[4][4][64][8];  // 16 KB
    int t = threadIdx.x;
    for (int idx = t; idx < 4096; idx += 256) {
        int j2 = idx & 3, l = (idx >> 2) & 63, ct = (idx >> 8) & 3, kk = idx >> 10;
        int k = kk * 32 + (l >> 4) * 8 + j2 * 2;
        int c = ct * 16 + (l & 15);
        ((unsigned*)w2p)[idx] = packbf(W2[k * OUT_DIM + c], W2[(k + 1) * OUT_DIM + c]);
    }
    int lane = t & 63, wave = t >> 6;
    int q = lane >> 4, m = lane & 15;
    __syncthreads();
    for (int blk = blockIdx.x * 4 + wave; blk < nblk; blk += gridDim.x * 4) {
        int r = blk * 16 + m;
        const short8* arow = (const short8*)(h1 + r * 64);
        short8 bfr[4];
#pragma unroll
        for (int kk = 0; kk < 4; kk++) bfr[kk] = arow[kk * 4 + q];
        floatx4 acc[4];
#pragma unroll
        for (int ct = 0; ct < 4; ct++) acc[ct] = (floatx4)0.0f;
#pragma unroll
        for (int kk = 0; kk < 4; kk++)
#pragma unroll
            for (int ct = 0; ct < 4; ct++) {
                short8 af = *(const short8*)(&w2p[kk][ct][lane][0]);
                acc[ct] = __builtin_amdgcn_mfma_f32_16x16x32_bf16(af, bfr[kk], acc[ct], 0, 0, 0);
            }
        unsigned* orow = h2 + r * 32;
#pragma unroll
        for (int ct = 0; ct < 4; ct++) {
            uint2 o;
            o.x = packbf(acc[ct][0], acc[ct][1]);
            o.y = packbf(acc[ct][2], acc[ct][3]);
            *(uint2*)(orow + ct * 8 + q * 2) = o;
        }
    }
}

extern "C" void kernel_launch(void* const* d_in, const int* in_sizes, int n_in,
                              void* d_out, int out_size, void* d_ws, size_t ws_size,
                              hipStream_t stream) {
    const float* x  = (const float*)d_in[0];
    const int*   ei = (const int*)d_in[1];
    const float* W1 = (const float*)d_in[2];
    const float* b1 = (const float*)d_in[3];
    const float* W2 = (const float*)d_in[4];
    const float* b2 = (const float*)d_in[5];

    // ---- layout (u32 units) ----
    const size_t OFF_FLAG = 0, OFF_DEG = 16, OFF_ROW = 100016, OFF_BSUM = 200032,
                 OFF_CSR = 200192, OFF_DINV = 1800192,
                 OFF_XB = 1900288,          // x bf16 [N,128] (6.4M u32); later h2 bf16 [N,64]
                 OFF_AGG = 8300288;         // epos(ushort) during CSR build; then aggx bf16 -> h1
    const size_t needed = (OFF_AGG + 6400000) * 4;  // 58,801,152 B
    if (ws_size < needed) return;  // canary: zero output, finite absmax

    int*      flag = (int*)d_ws + OFF_FLAG;
    int*      deg  = (int*)d_ws + OFF_DEG;
    int*      row  = (int*)d_ws + OFF_ROW;
    int*      bsum = (int*)d_ws + OFF_BSUM;
    int*      csr  = (int*)d_ws + OFF_CSR;
    float*    dinv = (float*)d_ws + OFF_DINV;
    unsigned* xb   = (unsigned*)d_ws + OFF_XB;
    unsigned* agg  = (unsigned*)d_ws + OFF_AGG;
    unsigned short* epos = (unsigned short*)agg;  // dead slot during CSR build

    // CSR build (single atomic pass)
    k_detect<<<1, 256, 0, stream>>>(ei, flag);
    hipMemsetAsync(deg, 0, N_NODES * sizeof(int), stream);
    k_deg_pos<<<(N_EDGES + 255) / 256, 256, 0, stream>>>(ei, flag, deg, epos);
    k_scan1<<<NBLK_SCAN, 256, 0, stream>>>(deg, row, bsum, dinv);
    k_scan2<<<1, 128, 0, stream>>>(bsum, row + N_NODES);
    k_scan3<<<(N_NODES + 255) / 256, 256, 0, stream>>>(row, bsum);
    k_fill<<<(N_EDGES + 255) / 256, 256, 0, stream>>>(ei, flag, row, epos, csr);

    // cast x to bf16
    k_cast_x<<<(N_NODES * (IN_DIM / 4) + 255) / 256, 256, 0, stream>>>(
        (const float4*)x, (uint2*)xb);

    // layer 1: pull-aggregate xb -> agg (bf16), MFMA GEMM in place (+bias+ELU)
    k_gather1<<<(N_NODES * 64 + 255) / 256, 256, 0, stream>>>(xb, dinv, row, csr, agg);
    k_gemm1_mfma<<<1024, 256, 0, stream>>>(agg, W1, b1, N_NODES / 16);

    // layer 2: MFMA GEMM h1 -> h2 (bf16, reuses xb slot), pull-aggregate + bias + ELU -> out
    k_gemm2_mfma<<<1024, 256, 0, stream>>>(agg, W2, xb, N_NODES / 16);
    k_gather2<<<(N_NODES * 32 + 255) / 256, 256, 0, stream>>>(
        xb, dinv, row, csr, b2, (float*)d_out);
}